// Round 21
// baseline (331.857 us; speedup 1.0000x reference)
//
#include <hip/hip_runtime.h>
#include <math.h>

// ---------------- problem constants ----------------
constexpr int B_    = 64;
constexpr int NPG_  = 2048;
constexpr int N_    = B_ * NPG_;        // 131072
constexpr int E_    = N_ * 16;          // 2097152
constexpr int EPG_  = NPG_ * 16;        // 32768 edges per graph (contiguous)
constexpr int BPG_  = 8;                // CSR blocks per graph
constexpr int EPB_  = EPG_ / BPG_;      // 4096 edges per CSR block
constexpr int NCSRB = B_ * BPG_;        // 512 CSR blocks
constexpr int NF_   = 128;
constexpr int EF_   = 32;
constexpr int TLD_  = 97;
constexpr int K_    = 30;
constexpr int C1_   = 16;
constexpr int C2_   = 32;
constexpr int KW2_  = 5;
constexpr int P2_   = 15;
constexpr int U_    = 11;
constexpr int DENSE_= C2_ * U_;         // 352
constexpr int HID_  = 128;
constexpr int NCLS_ = 10;
constexpr int CATLD = 128;              // padded leading dim for cat[N][97]

typedef float f4v __attribute__((ext_vector_type(4)));

__device__ __forceinline__ int cnt_of(float d) { return (int)(d + 0.5f) - 1; }

// XCD-aware bijective swizzle (grid divisible by 8)
__device__ __forceinline__ int xcd_swz(int bid, int nwg)
{
    int cpx = nwg >> 3;
    return (bid & 7) * cpx + (bid >> 3);
}

// ---------------- CSR build, atomic-free, packed adjacency ----------------
// adjp[slot] = (eid_local << 11) | col_local   (15 + 11 bits)
__global__ __launch_bounds__(256) void k_hist(const int* __restrict__ erow,
                                              int* __restrict__ hist)
{
    const int bid = blockIdx.x, tid = threadIdx.x;
    const int g = bid & 63, jb = bid >> 6;
    const int lb = g * BPG_ + jb;                 // logical block index
    const int base_e = g * EPG_ + jb * EPB_;
    const int base_n = g * NPG_;
    __shared__ int h[NPG_];
#pragma unroll
    for (int j = 0; j < NPG_ / 256; j++) h[tid + j * 256] = 0;
    __syncthreads();
#pragma unroll
    for (int j = 0; j < EPB_ / 256; j++)
        atomicAdd(&h[erow[base_e + tid + j * 256] - base_n], 1);
    __syncthreads();
#pragma unroll
    for (int j = 0; j < NPG_ / 256; j++)
        hist[lb * NPG_ + tid + j * 256] = h[tid + j * 256];
}

// per-graph prefix scan; one 64-block kernel.
__global__ __launch_bounds__(256) void k_scanall(const float* __restrict__ deg,
                                                 const int* __restrict__ hist,
                                                 int* __restrict__ row_start,
                                                 int* __restrict__ cursor_blk)
{
    const int g = blockIdx.x, t = threadIdx.x;
    __shared__ int rs[NPG_];
    __shared__ int wsum[4];
    __shared__ int carry;
    if (t == 0) carry = 0;
    __syncthreads();
    const int lane = t & 63, w = t >> 6;
#pragma unroll
    for (int c = 0; c < NPG_ / 256; c++) {
        int r = c * 256 + t;
        int cnt = cnt_of(deg[g * NPG_ + r]);
        int sc = cnt;
#pragma unroll
        for (int d = 1; d < 64; d <<= 1) {
            int v = __shfl_up(sc, d);
            if (lane >= d) sc += v;
        }
        if (lane == 63) wsum[w] = sc;
        __syncthreads();
        int woff = carry;
        for (int k = 0; k < w; k++) woff += wsum[k];
        rs[r] = woff + sc - cnt;
        __syncthreads();
        if (t == 0) carry += wsum[0] + wsum[1] + wsum[2] + wsum[3];
        __syncthreads();
    }
    const int base_e = g * EPG_;
    for (int r = t; r < NPG_; r += 256) {
        int acc = base_e + rs[r];
        row_start[g * NPG_ + r] = acc;
#pragma unroll
        for (int b = 0; b < BPG_; b++) {
            int idx = (g * BPG_ + b) * NPG_ + r;
            cursor_blk[idx] = acc;
            acc += hist[idx];
        }
    }
}

__global__ __launch_bounds__(256) void k_fillc(const int* __restrict__ erow,
                                               const int* __restrict__ ecol,
                                               const int* __restrict__ cursor_blk,
                                               unsigned int* __restrict__ adjp)
{
    const int bid = blockIdx.x, tid = threadIdx.x;
    const int g = bid & 63, jb = bid >> 6;
    const int lb = g * BPG_ + jb;
    const int base_e = g * EPG_ + jb * EPB_;
    const int base_eg = g * EPG_;
    const int base_n = g * NPG_;
    __shared__ int cur[NPG_];
#pragma unroll
    for (int j = 0; j < NPG_ / 256; j++)
        cur[tid + j * 256] = cursor_blk[lb * NPG_ + tid + j * 256];
    __syncthreads();
#pragma unroll
    for (int j = 0; j < EPB_ / 256; j++) {
        int e = base_e + tid + j * 256;
        int r = erow[e] - base_n;
        int slot = atomicAdd(&cur[r], 1);
        adjp[slot] = ((unsigned int)(e - base_eg) << 11) | (unsigned int)(ecol[e] - base_n);
    }
}

// ---------------- e2n gather: float4 lanes, packed adj (HBM-bound; single-row) ----------------
__global__ __launch_bounds__(256) void k_e2n_gather(const float* __restrict__ ef,
                                                    const int* __restrict__ row_start,
                                                    const float* __restrict__ deg,
                                                    const unsigned int* __restrict__ adjp,
                                                    float* __restrict__ e2n)
{
    int gid = xcd_swz(blockIdx.x, gridDim.x) * 256 + threadIdx.x;   // N*32 threads
    int i = gid >> 5, o = gid & 31;
    int s = row_start[i];
    int n = cnt_of(deg[i]);
    const long base_eg = (long)(i >> 11) * EPG_;
    const int sub = o >> 3, comp = o & 7;
    const f4v* ef4 = reinterpret_cast<const f4v*>(ef);
    f4v acc = {0.f, 0.f, 0.f, 0.f};
    for (int base = 0; base < n; base += 32) {
        int m = n - base; int mi = (m > 32) ? 32 : m;   // >= 1
        unsigned int pv = adjp[s + base + ((o < mi) ? o : (mi - 1))];
#pragma unroll
        for (int t = 0; t < 8; t++) {
            int kk = 4 * t + sub;
            unsigned int vv = __shfl(pv, kk, 32);
            long e = base_eg + (vv >> 11);
            float w = (kk < mi) ? 1.f : 0.f;
            f4v v = __builtin_nontemporal_load(ef4 + e * 8 + comp);
            acc += w * v;
        }
    }
    acc.x += __shfl_xor(acc.x, 8, 32);  acc.y += __shfl_xor(acc.y, 8, 32);
    acc.z += __shfl_xor(acc.z, 8, 32);  acc.w += __shfl_xor(acc.w, 8, 32);
    acc.x += __shfl_xor(acc.x, 16, 32); acc.y += __shfl_xor(acc.y, 16, 32);
    acc.z += __shfl_xor(acc.z, 16, 32); acc.w += __shfl_xor(acc.w, 16, 32);
    if (o < 8)
        reinterpret_cast<f4v*>(e2n)[(long)i * 8 + o] = acc;
}

// ---------------- quad gather core: four independent rows per 32-lane group ----------------
// ~36 loads in flight per lane; four independent reduce trees.
__device__ __forceinline__ void row_gather_quad(const unsigned int* __restrict__ adjp,
                                                int s0, int n0, int s1, int n1,
                                                int s2, int n2, int s3, int n3, int bng,
                                                const f4v* __restrict__ p4, int o,
                                                float& out0, float& out1,
                                                float& out2, float& out3)
{
    const int sub = o >> 3, comp = o & 7;
    f4v acc0 = {0.f,0.f,0.f,0.f}, acc1 = {0.f,0.f,0.f,0.f};
    f4v acc2 = {0.f,0.f,0.f,0.f}, acc3 = {0.f,0.f,0.f,0.f};
    int c0n = (n0 + 31) >> 5, c1n = (n1 + 31) >> 5;
    int c2n = (n2 + 31) >> 5, c3n = (n3 + 31) >> 5;
    int mc01 = (c0n > c1n) ? c0n : c1n;
    int mc23 = (c2n > c3n) ? c2n : c3n;
    int mc = (mc01 > mc23) ? mc01 : mc23;
    for (int ci = 0; ci < mc; ci++) {
        int base = ci * 32;
        if (ci < c0n) {
            int m = n0 - base; int mi = (m > 32) ? 32 : m;
            unsigned int pv = adjp[s0 + base + ((o < mi) ? o : (mi - 1))];
#pragma unroll
            for (int t = 0; t < 8; t++) {
                int kk = 4 * t + sub;
                unsigned int vv = __shfl(pv, kk, 32);
                int c = bng + (int)(vv & 2047u);
                float w = (kk < mi) ? 1.f : 0.f;
                acc0 += w * p4[(long)c * 8 + comp];
            }
        }
        if (ci < c1n) {
            int m = n1 - base; int mi = (m > 32) ? 32 : m;
            unsigned int pv = adjp[s1 + base + ((o < mi) ? o : (mi - 1))];
#pragma unroll
            for (int t = 0; t < 8; t++) {
                int kk = 4 * t + sub;
                unsigned int vv = __shfl(pv, kk, 32);
                int c = bng + (int)(vv & 2047u);
                float w = (kk < mi) ? 1.f : 0.f;
                acc1 += w * p4[(long)c * 8 + comp];
            }
        }
        if (ci < c2n) {
            int m = n2 - base; int mi = (m > 32) ? 32 : m;
            unsigned int pv = adjp[s2 + base + ((o < mi) ? o : (mi - 1))];
#pragma unroll
            for (int t = 0; t < 8; t++) {
                int kk = 4 * t + sub;
                unsigned int vv = __shfl(pv, kk, 32);
                int c = bng + (int)(vv & 2047u);
                float w = (kk < mi) ? 1.f : 0.f;
                acc2 += w * p4[(long)c * 8 + comp];
            }
        }
        if (ci < c3n) {
            int m = n3 - base; int mi = (m > 32) ? 32 : m;
            unsigned int pv = adjp[s3 + base + ((o < mi) ? o : (mi - 1))];
#pragma unroll
            for (int t = 0; t < 8; t++) {
                int kk = 4 * t + sub;
                unsigned int vv = __shfl(pv, kk, 32);
                int c = bng + (int)(vv & 2047u);
                float w = (kk < mi) ? 1.f : 0.f;
                acc3 += w * p4[(long)c * 8 + comp];
            }
        }
    }
#define RG_RED(A) \
    A.x += __shfl_xor(A.x, 8, 32);  A.y += __shfl_xor(A.y, 8, 32); \
    A.z += __shfl_xor(A.z, 8, 32);  A.w += __shfl_xor(A.w, 8, 32); \
    A.x += __shfl_xor(A.x, 16, 32); A.y += __shfl_xor(A.y, 16, 32); \
    A.z += __shfl_xor(A.z, 16, 32); A.w += __shfl_xor(A.w, 16, 32);
    RG_RED(acc0) RG_RED(acc1) RG_RED(acc2) RG_RED(acc3)
#undef RG_RED
    int src = o >> 2, el = o & 3;
#define RG_EXT(A, OUT) { \
    float _a = __shfl(A.x, src, 32), _b = __shfl(A.y, src, 32); \
    float _c = __shfl(A.z, src, 32), _d = __shfl(A.w, src, 32); \
    OUT = (el == 0) ? _a : (el == 1) ? _b : (el == 2) ? _c : _d; }
    RG_EXT(acc0, out0) RG_EXT(acc1, out1) RG_EXT(acc2, out2) RG_EXT(acc3, out3)
#undef RG_EXT
}

// ---------------- layer 0 GEMM: p = [nf | e2n] @ W0^T ----------------
__global__ __launch_bounds__(256) void k_gemm0(const float* __restrict__ nf,
                                               const float* __restrict__ e2n,
                                               const float* __restrict__ W0,
                                               float* __restrict__ p)
{
    __shared__ float Ws[32 * 160];
    for (int t = threadIdx.x; t < 32 * 160; t += 256) Ws[t] = W0[t];
    __syncthreads();
    int i = blockIdx.x * 256 + threadIdx.x;
    float acc[32];
#pragma unroll
    for (int o = 0; o < 32; o++) acc[o] = 0.f;
    const float4* row  = reinterpret_cast<const float4*>(nf  + (long)i * NF_);
    const float4* row2 = reinterpret_cast<const float4*>(e2n + (long)i * EF_);
    const float4* Ws4  = reinterpret_cast<const float4*>(Ws);
    for (int d4 = 0; d4 < NF_ / 4; ++d4) {
        float4 v = row[d4];
#pragma unroll
        for (int o = 0; o < 32; o++) {
            float4 w = Ws4[o * 40 + d4];
            acc[o] += v.x * w.x + v.y * w.y + v.z * w.z + v.w * w.w;
        }
    }
#pragma unroll
    for (int d4 = 0; d4 < EF_ / 4; ++d4) {
        float4 v = row2[d4];
#pragma unroll
        for (int o = 0; o < 32; o++) {
            float4 w = Ws4[o * 40 + 32 + d4];
            acc[o] += v.x * w.x + v.y * w.y + v.z * w.z + v.w * w.w;
        }
    }
    float4* p4 = reinterpret_cast<float4*>(p + (long)i * 32);
#pragma unroll
    for (int o4 = 0; o4 < 8; o4++)
        p4[o4] = make_float4(acc[o4*4], acc[o4*4+1], acc[o4*4+2], acc[o4*4+3]);
}

// ---------------- fused: quad-gather + tanh + NEXT-layer projection ----------------
__global__ __launch_bounds__(256) void k_gather_proj(const int* __restrict__ row_start,
                                                     const unsigned int* __restrict__ adjp,
                                                     const float* __restrict__ deg,
                                                     const float* __restrict__ p_in,
                                                     const float* __restrict__ b,
                                                     float* __restrict__ cat, int out_off,
                                                     const float* __restrict__ Wn,
                                                     float* __restrict__ p_out)
{
    __shared__ float WT[32 * 32];
    for (int idx = threadIdx.x; idx < 1024; idx += 256) {
        int k = idx >> 5, o = idx & 31;
        WT[idx] = Wn[o * 32 + k];
    }
    __syncthreads();
    int gid = xcd_swz(blockIdx.x, gridDim.x) * 256 + threadIdx.x;   // (N/4)*32 threads
    int qr = gid >> 5, o = gid & 31;
    int i0 = qr * 4, i1 = i0 + 1, i2 = i0 + 2, i3 = i0 + 3;
    int s0 = row_start[i0], s1 = row_start[i1], s2 = row_start[i2], s3 = row_start[i3];
    float dg0 = deg[i0], dg1 = deg[i1], dg2 = deg[i2], dg3 = deg[i3];
    int n0 = cnt_of(dg0), n1 = cnt_of(dg1), n2 = cnt_of(dg2), n3 = cnt_of(dg3);
    int bng = i0 & ~2047;
    float r0, r1, r2, r3;
    row_gather_quad(adjp, s0, n0, s1, n1, s2, n2, s3, n3, bng,
                    reinterpret_cast<const f4v*>(p_in), o, r0, r1, r2, r3);
    float bo = b[o];
    float t0 = tanhf((p_in[(long)i0 * 32 + o] + r0 + bo) / dg0);
    float t1 = tanhf((p_in[(long)i1 * 32 + o] + r1 + bo) / dg1);
    float t2 = tanhf((p_in[(long)i2 * 32 + o] + r2 + bo) / dg2);
    float t3 = tanhf((p_in[(long)i3 * 32 + o] + r3 + bo) / dg3);
    __builtin_nontemporal_store(t0, &cat[(long)i0 * CATLD + out_off + o]);
    __builtin_nontemporal_store(t1, &cat[(long)i1 * CATLD + out_off + o]);
    __builtin_nontemporal_store(t2, &cat[(long)i2 * CATLD + out_off + o]);
    __builtin_nontemporal_store(t3, &cat[(long)i3 * CATLD + out_off + o]);
    float a0 = 0.f, a1 = 0.f, a2 = 0.f, a3 = 0.f;
#pragma unroll
    for (int k = 0; k < 32; k++) {
        float w = WT[k * 32 + o];
        a0 += __shfl(t0, k, 32) * w;
        a1 += __shfl(t1, k, 32) * w;
        a2 += __shfl(t2, k, 32) * w;
        a3 += __shfl(t3, k, 32) * w;
    }
    p_out[(long)i0 * 32 + o] = a0;
    p_out[(long)i1 * 32 + o] = a1;
    p_out[(long)i2 * 32 + o] = a2;
    p_out[(long)i3 * 32 + o] = a3;
}

// ---------------- quad-gather + tanh + 1-wide W3 projection (layer 2) ----------------
__global__ __launch_bounds__(256) void k_gather_act32(const int* __restrict__ row_start,
                                                      const unsigned int* __restrict__ adjp,
                                                      const float* __restrict__ deg,
                                                      const float* __restrict__ p,
                                                      const float* __restrict__ b,
                                                      float* __restrict__ cat, int out_off,
                                                      const float* __restrict__ W3,
                                                      float* __restrict__ p1)
{
    int gid = xcd_swz(blockIdx.x, gridDim.x) * 256 + threadIdx.x;   // (N/4)*32 threads
    int qr = gid >> 5, o = gid & 31;
    int i0 = qr * 4, i1 = i0 + 1, i2 = i0 + 2, i3 = i0 + 3;
    int s0 = row_start[i0], s1 = row_start[i1], s2 = row_start[i2], s3 = row_start[i3];
    float dg0 = deg[i0], dg1 = deg[i1], dg2 = deg[i2], dg3 = deg[i3];
    int n0 = cnt_of(dg0), n1 = cnt_of(dg1), n2 = cnt_of(dg2), n3 = cnt_of(dg3);
    int bng = i0 & ~2047;
    float r0, r1, r2, r3;
    row_gather_quad(adjp, s0, n0, s1, n1, s2, n2, s3, n3, bng,
                    reinterpret_cast<const f4v*>(p), o, r0, r1, r2, r3);
    float bo = b[o];
    float t0 = tanhf((p[(long)i0 * 32 + o] + r0 + bo) / dg0);
    float t1 = tanhf((p[(long)i1 * 32 + o] + r1 + bo) / dg1);
    float t2 = tanhf((p[(long)i2 * 32 + o] + r2 + bo) / dg2);
    float t3 = tanhf((p[(long)i3 * 32 + o] + r3 + bo) / dg3);
    __builtin_nontemporal_store(t0, &cat[(long)i0 * CATLD + out_off + o]);
    __builtin_nontemporal_store(t1, &cat[(long)i1 * CATLD + out_off + o]);
    __builtin_nontemporal_store(t2, &cat[(long)i2 * CATLD + out_off + o]);
    __builtin_nontemporal_store(t3, &cat[(long)i3 * CATLD + out_off + o]);
    float w3 = W3[o];
    float q0 = t0 * w3, q1 = t1 * w3, q2 = t2 * w3, q3 = t3 * w3;
#pragma unroll
    for (int sft = 16; sft > 0; sft >>= 1) {
        q0 += __shfl_xor(q0, sft, 32);
        q1 += __shfl_xor(q1, sft, 32);
        q2 += __shfl_xor(q2, sft, 32);
        q3 += __shfl_xor(q3, sft, 32);
    }
    if (o == 0) { p1[i0] = q0; p1[i1] = q1; p1[i2] = q2; p1[i3] = q3; }
}

// ---------------- layer 3 gather + act (1-wide, chunk-8) -> DENSE t3 ----------------
__global__ __launch_bounds__(256) void k_gather_act1(const int* __restrict__ row_start,
                                                     const unsigned int* __restrict__ adjp,
                                                     const float* __restrict__ deg,
                                                     const float* __restrict__ p1,
                                                     const float* __restrict__ b,
                                                     float* __restrict__ t3)
{
    int i = blockIdx.x * 256 + threadIdx.x;     // N threads
    int s = row_start[i];
    float dg = deg[i];
    int n = cnt_of(dg);
    int bn = i & ~2047;
    float a = p1[i];
    int k = 0;
    for (; k + 8 <= n; k += 8) {
        unsigned int v0 = adjp[s + k + 0], v1 = adjp[s + k + 1], v2 = adjp[s + k + 2], v3 = adjp[s + k + 3];
        unsigned int v4 = adjp[s + k + 4], v5 = adjp[s + k + 5], v6 = adjp[s + k + 6], v7 = adjp[s + k + 7];
        float f0 = p1[bn + (v0 & 2047u)], f1 = p1[bn + (v1 & 2047u)];
        float f2 = p1[bn + (v2 & 2047u)], f3 = p1[bn + (v3 & 2047u)];
        float f4 = p1[bn + (v4 & 2047u)], f5 = p1[bn + (v5 & 2047u)];
        float f6 = p1[bn + (v6 & 2047u)], f7 = p1[bn + (v7 & 2047u)];
        a += ((f0 + f1) + (f2 + f3)) + ((f4 + f5) + (f6 + f7));
    }
    for (; k < n; k++) a += p1[bn + (adjp[s + k] & 2047u)];
    t3[i] = tanhf((a + b[0]) / dg);
}

// ---------------- sortpooling top-K + conv/MLP head (one block per graph) ----------------
__global__ __launch_bounds__(256) void k_topk_head(
    const float* __restrict__ t3,
    const float* __restrict__ cat,
    const float* __restrict__ Wc1, const float* __restrict__ bc1,
    const float* __restrict__ Wc2, const float* __restrict__ bc2,
    const float* __restrict__ Wh,  const float* __restrict__ bh,
    const float* __restrict__ Wo,  const float* __restrict__ bo,
    float* __restrict__ out)
{
    const int g = blockIdx.x, tid = threadIdx.x;
    __shared__ float vals[NPG_];
    __shared__ int   sel[K_];
    __shared__ float selv[K_];
    __shared__ float Pm[K_][TLD_];
    __shared__ float y1[C1_][K_];
    __shared__ float y2[C1_][P2_];
    __shared__ float dd[DENSE_];
    __shared__ float h1s[HID_];
    __shared__ float zz[NCLS_];
    const long gbase = (long)g * NPG_;

    for (int j = tid; j < NPG_; j += 256) vals[j] = t3[gbase + j];
    __syncthreads();

    // top-K, ties -> lower index (jax.lax.top_k semantics); wave 0 only, no barriers
    if (tid < 64) {
        for (int k = 0; k < K_; k++) {
            float bv = -INFINITY; int bj = NPG_;
#pragma unroll
            for (int m = 0; m < 32; m++) {
                int j = m * 64 + tid;               // ascending j per lane -> strict > keeps lowest
                float v = vals[j];
                if (v > bv) { bv = v; bj = j; }
            }
#pragma unroll
            for (int s = 32; s > 0; s >>= 1) {
                float ov = __shfl_xor(bv, s);
                int   oj = __shfl_xor(bj, s);
                if (ov > bv || (ov == bv && oj < bj)) { bv = ov; bj = oj; }
            }
            if (tid == 0) { sel[k] = bj; selv[k] = bv; vals[bj] = -INFINITY; }
        }
    }
    __syncthreads();

    for (int t = tid; t < K_ * TLD_; t += 256) {
        int k = t / TLD_, d = t % TLD_;
        Pm[k][d] = (d < 96) ? cat[(gbase + sel[k]) * CATLD + d] : selv[k];
    }
    __syncthreads();

    for (int t = tid; t < C1_ * K_; t += 256) {
        int c = t / K_, k = t % K_;
        float a = bc1[c];
        for (int d = 0; d < TLD_; d++) a += Pm[k][d] * Wc1[c * TLD_ + d];
        y1[c][k] = fmaxf(a, 0.f);
    }
    __syncthreads();

    for (int t = tid; t < C1_ * P2_; t += 256) {
        int c = t / P2_, u = t % P2_;
        y2[c][u] = fmaxf(y1[c][2 * u], y1[c][2 * u + 1]);
    }
    __syncthreads();

    for (int t = tid; t < C2_ * U_; t += 256) {
        int c2 = t / U_, u = t % U_;
        float a = bc2[c2];
        for (int c = 0; c < C1_; c++)
#pragma unroll
            for (int w = 0; w < KW2_; w++)
                a += y2[c][u + w] * Wc2[(c2 * C1_ + c) * KW2_ + w];
        dd[t] = fmaxf(a, 0.f);
    }
    __syncthreads();

    if (tid < HID_) {
        float a = bh[tid];
        for (int i = 0; i < DENSE_; i++) a += dd[i] * Wh[tid * DENSE_ + i];
        h1s[tid] = fmaxf(a, 0.f);
    }
    __syncthreads();

    if (tid < NCLS_) {
        float a = bo[tid];
        for (int j = 0; j < HID_; j++) a += h1s[j] * Wo[tid * HID_ + j];
        zz[tid] = a;
    }
    __syncthreads();

    if (tid == 0) {
        float m = zz[0];
        for (int c = 1; c < NCLS_; c++) m = fmaxf(m, zz[c]);
        float s = 0.f;
        for (int c = 0; c < NCLS_; c++) s += expf(zz[c] - m);
        float lse = m + logf(s);
        for (int c = 0; c < NCLS_; c++) out[g * NCLS_ + c] = zz[c] - lse;
    }
}

// ---------------- host launch ----------------
extern "C" void kernel_launch(void* const* d_in, const int* in_sizes, int n_in,
                              void* d_out, int out_size, void* d_ws, size_t ws_size,
                              hipStream_t stream)
{
    const float* nf  = (const float*)d_in[0];
    const float* ef  = (const float*)d_in[1];
    const float* deg = (const float*)d_in[2];
    const float* W0  = (const float*)d_in[3];  const float* b0  = (const float*)d_in[4];
    const float* W1  = (const float*)d_in[5];  const float* b1  = (const float*)d_in[6];
    const float* W2  = (const float*)d_in[7];  const float* b2  = (const float*)d_in[8];
    const float* W3  = (const float*)d_in[9];  const float* b3  = (const float*)d_in[10];
    const float* Wc1 = (const float*)d_in[11]; const float* bc1 = (const float*)d_in[12];
    const float* Wc2 = (const float*)d_in[13]; const float* bc2 = (const float*)d_in[14];
    const float* Wh  = (const float*)d_in[15]; const float* bh  = (const float*)d_in[16];
    const float* Wo  = (const float*)d_in[17]; const float* bo  = (const float*)d_in[18];
    const int* erow  = (const int*)d_in[19];
    const int* ecol  = (const int*)d_in[20];
    float* out = (float*)d_out;

    // ---- workspace layout ----
    char* wsb = (char*)d_ws;
    float* e2n       = (float*)wsb;                       wsb += (size_t)N_ * 32 * 4;   // 16 MB
    float* pA        = (float*)wsb;                       wsb += (size_t)N_ * 32 * 4;   // 16 MB
    float* pB        = (float*)wsb;                       wsb += (size_t)N_ * 32 * 4;   // 16 MB
    float* cat       = (float*)wsb;                       wsb += (size_t)N_ * CATLD * 4;// 64 MB
    float* p1        = (float*)wsb;                       wsb += (size_t)N_ * 4;        // 0.5 MB
    float* t3        = (float*)wsb;                       wsb += (size_t)N_ * 4;        // 0.5 MB
    int*   row_start = (int*)wsb;                         wsb += (size_t)N_ * 4;
    unsigned int* adjp = (unsigned int*)wsb;              /* 8 MB */

    // hist / cursor_blk (4 MB each) overlay pA / pB — both dead until k_gemm0 / k_gather_proj
    int* hist       = (int*)pA;
    int* cursor_blk = (int*)pB;

    // ---- CSR build, atomic-free, XCD-co-located, packed ----
    k_hist<<<NCSRB, 256, 0, stream>>>(erow, hist);
    k_scanall<<<B_, 256, 0, stream>>>(deg, hist, row_start, cursor_blk);
    k_fillc<<<NCSRB, 256, 0, stream>>>(erow, ecol, cursor_blk, adjp);

    // ---- e2n via gather ----
    k_e2n_gather<<<N_ * 32 / 256, 256, 0, stream>>>(ef, row_start, deg, adjp, e2n);

    // ---- layer 0 projection ----
    k_gemm0<<<N_ / 256, 256, 0, stream>>>(nf, e2n, W0, pA);
    // ---- layer 0 pool/act + W1 projection (4 rows per lane-group) ----
    k_gather_proj<<<N_ * 8 / 256, 256, 0, stream>>>(row_start, adjp, deg, pA, b0, cat, 0, W1, pB);
    // ---- layer 1 pool/act + W2 projection ----
    k_gather_proj<<<N_ * 8 / 256, 256, 0, stream>>>(row_start, adjp, deg, pB, b1, cat, 32, W2, pA);
    // ---- layer 2 pool/act + W3 projection (1-wide) ----
    k_gather_act32<<<N_ * 8 / 256, 256, 0, stream>>>(row_start, adjp, deg, pA, b2, cat, 64, W3, p1);
    // ---- layer 3 pool/act -> dense t3 ----
    k_gather_act1<<<N_ / 256, 256, 0, stream>>>(row_start, adjp, deg, p1, b3, t3);

    // ---- sortpooling + head ----
    k_topk_head<<<B_, 256, 0, stream>>>(t3, cat, Wc1, bc1, Wc2, bc2, Wh, bh, Wo, bo, out);
}

// Round 22
// 326.144 us; speedup vs baseline: 1.0175x; 1.0175x over previous
//
#include <hip/hip_runtime.h>
#include <math.h>

// ---------------- problem constants ----------------
constexpr int B_    = 64;
constexpr int NPG_  = 2048;
constexpr int N_    = B_ * NPG_;        // 131072
constexpr int E_    = N_ * 16;          // 2097152
constexpr int EPG_  = NPG_ * 16;        // 32768 edges per graph (contiguous)
constexpr int BPG_  = 8;                // CSR blocks per graph
constexpr int EPB_  = EPG_ / BPG_;      // 4096 edges per CSR block
constexpr int NCSRB = B_ * BPG_;        // 512 CSR blocks
constexpr int NF_   = 128;
constexpr int EF_   = 32;
constexpr int TLD_  = 97;
constexpr int K_    = 30;
constexpr int C1_   = 16;
constexpr int C2_   = 32;
constexpr int KW2_  = 5;
constexpr int P2_   = 15;
constexpr int U_    = 11;
constexpr int DENSE_= C2_ * U_;         // 352
constexpr int HID_  = 128;
constexpr int NCLS_ = 10;
constexpr int CATLD = 128;              // padded leading dim for cat[N][97]

typedef float f4v __attribute__((ext_vector_type(4)));

__device__ __forceinline__ int cnt_of(float d) { return (int)(d + 0.5f) - 1; }

// XCD-aware bijective swizzle (grid divisible by 8)
__device__ __forceinline__ int xcd_swz(int bid, int nwg)
{
    int cpx = nwg >> 3;
    return (bid & 7) * cpx + (bid >> 3);
}

// ---------------- CSR build, atomic-free, packed adjacency ----------------
// adjp[slot] = (eid_local << 11) | col_local   (15 + 11 bits)
__global__ __launch_bounds__(256) void k_hist(const int* __restrict__ erow,
                                              int* __restrict__ hist)
{
    const int bid = blockIdx.x, tid = threadIdx.x;
    const int g = bid & 63, jb = bid >> 6;
    const int lb = g * BPG_ + jb;                 // logical block index
    const int base_e = g * EPG_ + jb * EPB_;
    const int base_n = g * NPG_;
    __shared__ int h[NPG_];
#pragma unroll
    for (int j = 0; j < NPG_ / 256; j++) h[tid + j * 256] = 0;
    __syncthreads();
#pragma unroll
    for (int j = 0; j < EPB_ / 256; j++)
        atomicAdd(&h[erow[base_e + tid + j * 256] - base_n], 1);
    __syncthreads();
#pragma unroll
    for (int j = 0; j < NPG_ / 256; j++)
        hist[lb * NPG_ + tid + j * 256] = h[tid + j * 256];
}

// per-graph prefix scan; one 64-block kernel.
__global__ __launch_bounds__(256) void k_scanall(const float* __restrict__ deg,
                                                 const int* __restrict__ hist,
                                                 int* __restrict__ row_start,
                                                 int* __restrict__ cursor_blk)
{
    const int g = blockIdx.x, t = threadIdx.x;
    __shared__ int rs[NPG_];
    __shared__ int wsum[4];
    __shared__ int carry;
    if (t == 0) carry = 0;
    __syncthreads();
    const int lane = t & 63, w = t >> 6;
#pragma unroll
    for (int c = 0; c < NPG_ / 256; c++) {
        int r = c * 256 + t;
        int cnt = cnt_of(deg[g * NPG_ + r]);
        int sc = cnt;
#pragma unroll
        for (int d = 1; d < 64; d <<= 1) {
            int v = __shfl_up(sc, d);
            if (lane >= d) sc += v;
        }
        if (lane == 63) wsum[w] = sc;
        __syncthreads();
        int woff = carry;
        for (int k = 0; k < w; k++) woff += wsum[k];
        rs[r] = woff + sc - cnt;
        __syncthreads();
        if (t == 0) carry += wsum[0] + wsum[1] + wsum[2] + wsum[3];
        __syncthreads();
    }
    const int base_e = g * EPG_;
    for (int r = t; r < NPG_; r += 256) {
        int acc = base_e + rs[r];
        row_start[g * NPG_ + r] = acc;
#pragma unroll
        for (int b = 0; b < BPG_; b++) {
            int idx = (g * BPG_ + b) * NPG_ + r;
            cursor_blk[idx] = acc;
            acc += hist[idx];
        }
    }
}

__global__ __launch_bounds__(256) void k_fillc(const int* __restrict__ erow,
                                               const int* __restrict__ ecol,
                                               const int* __restrict__ cursor_blk,
                                               unsigned int* __restrict__ adjp)
{
    const int bid = blockIdx.x, tid = threadIdx.x;
    const int g = bid & 63, jb = bid >> 6;
    const int lb = g * BPG_ + jb;
    const int base_e = g * EPG_ + jb * EPB_;
    const int base_eg = g * EPG_;
    const int base_n = g * NPG_;
    __shared__ int cur[NPG_];
#pragma unroll
    for (int j = 0; j < NPG_ / 256; j++)
        cur[tid + j * 256] = cursor_blk[lb * NPG_ + tid + j * 256];
    __syncthreads();
#pragma unroll
    for (int j = 0; j < EPB_ / 256; j++) {
        int e = base_e + tid + j * 256;
        int r = erow[e] - base_n;
        int slot = atomicAdd(&cur[r], 1);
        adjp[slot] = ((unsigned int)(e - base_eg) << 11) | (unsigned int)(ecol[e] - base_n);
    }
}

// ---------------- e2n gather: float4 lanes, packed adj (HBM-bound; single-row) ----------------
__global__ __launch_bounds__(256) void k_e2n_gather(const float* __restrict__ ef,
                                                    const int* __restrict__ row_start,
                                                    const float* __restrict__ deg,
                                                    const unsigned int* __restrict__ adjp,
                                                    float* __restrict__ e2n)
{
    int gid = xcd_swz(blockIdx.x, gridDim.x) * 256 + threadIdx.x;   // N*32 threads
    int i = gid >> 5, o = gid & 31;
    int s = row_start[i];
    int n = cnt_of(deg[i]);
    const long base_eg = (long)(i >> 11) * EPG_;
    const int sub = o >> 3, comp = o & 7;
    const f4v* ef4 = reinterpret_cast<const f4v*>(ef);
    f4v acc = {0.f, 0.f, 0.f, 0.f};
    for (int base = 0; base < n; base += 32) {
        int m = n - base; int mi = (m > 32) ? 32 : m;   // >= 1
        unsigned int pv = adjp[s + base + ((o < mi) ? o : (mi - 1))];
#pragma unroll
        for (int t = 0; t < 8; t++) {
            int kk = 4 * t + sub;
            unsigned int vv = __shfl(pv, kk, 32);
            long e = base_eg + (vv >> 11);
            float w = (kk < mi) ? 1.f : 0.f;
            f4v v = __builtin_nontemporal_load(ef4 + e * 8 + comp);
            acc += w * v;
        }
    }
    acc.x += __shfl_xor(acc.x, 8, 32);  acc.y += __shfl_xor(acc.y, 8, 32);
    acc.z += __shfl_xor(acc.z, 8, 32);  acc.w += __shfl_xor(acc.w, 8, 32);
    acc.x += __shfl_xor(acc.x, 16, 32); acc.y += __shfl_xor(acc.y, 16, 32);
    acc.z += __shfl_xor(acc.z, 16, 32); acc.w += __shfl_xor(acc.w, 16, 32);
    if (o < 8)
        reinterpret_cast<f4v*>(e2n)[(long)i * 8 + o] = acc;
}

// ---------------- pair gather core: two independent rows per 32-lane group ----------------
// 18 loads in flight per lane (vs 9 single-row); independent reduce trees.
__device__ __forceinline__ void row_gather_pair(const unsigned int* __restrict__ adjp,
                                                int s0, int n0, int s1, int n1, int bng,
                                                const f4v* __restrict__ p4, int o,
                                                float& out0, float& out1)
{
    const int sub = o >> 3, comp = o & 7;
    f4v acc0 = {0.f, 0.f, 0.f, 0.f};
    f4v acc1 = {0.f, 0.f, 0.f, 0.f};
    int c0n = (n0 + 31) >> 5, c1n = (n1 + 31) >> 5;
    int mc = (c0n > c1n) ? c0n : c1n;
    for (int ci = 0; ci < mc; ci++) {
        int base = ci * 32;
        if (ci < c0n) {
            int m = n0 - base; int mi = (m > 32) ? 32 : m;
            unsigned int pv = adjp[s0 + base + ((o < mi) ? o : (mi - 1))];
#pragma unroll
            for (int t = 0; t < 8; t++) {
                int kk = 4 * t + sub;
                unsigned int vv = __shfl(pv, kk, 32);
                int c = bng + (int)(vv & 2047u);
                float w = (kk < mi) ? 1.f : 0.f;
                acc0 += w * p4[(long)c * 8 + comp];
            }
        }
        if (ci < c1n) {
            int m = n1 - base; int mi = (m > 32) ? 32 : m;
            unsigned int pv = adjp[s1 + base + ((o < mi) ? o : (mi - 1))];
#pragma unroll
            for (int t = 0; t < 8; t++) {
                int kk = 4 * t + sub;
                unsigned int vv = __shfl(pv, kk, 32);
                int c = bng + (int)(vv & 2047u);
                float w = (kk < mi) ? 1.f : 0.f;
                acc1 += w * p4[(long)c * 8 + comp];
            }
        }
    }
    acc0.x += __shfl_xor(acc0.x, 8, 32);  acc0.y += __shfl_xor(acc0.y, 8, 32);
    acc0.z += __shfl_xor(acc0.z, 8, 32);  acc0.w += __shfl_xor(acc0.w, 8, 32);
    acc1.x += __shfl_xor(acc1.x, 8, 32);  acc1.y += __shfl_xor(acc1.y, 8, 32);
    acc1.z += __shfl_xor(acc1.z, 8, 32);  acc1.w += __shfl_xor(acc1.w, 8, 32);
    acc0.x += __shfl_xor(acc0.x, 16, 32); acc0.y += __shfl_xor(acc0.y, 16, 32);
    acc0.z += __shfl_xor(acc0.z, 16, 32); acc0.w += __shfl_xor(acc0.w, 16, 32);
    acc1.x += __shfl_xor(acc1.x, 16, 32); acc1.y += __shfl_xor(acc1.y, 16, 32);
    acc1.z += __shfl_xor(acc1.z, 16, 32); acc1.w += __shfl_xor(acc1.w, 16, 32);
    int src = o >> 2, el = o & 3;
    float a0 = __shfl(acc0.x, src, 32), b0 = __shfl(acc0.y, src, 32);
    float c0 = __shfl(acc0.z, src, 32), d0 = __shfl(acc0.w, src, 32);
    float a1 = __shfl(acc1.x, src, 32), b1 = __shfl(acc1.y, src, 32);
    float c1 = __shfl(acc1.z, src, 32), d1 = __shfl(acc1.w, src, 32);
    out0 = (el == 0) ? a0 : (el == 1) ? b0 : (el == 2) ? c0 : d0;
    out1 = (el == 0) ? a1 : (el == 1) ? b1 : (el == 2) ? c1 : d1;
}

// ---------------- layer 0 GEMM: p = [nf | e2n] @ W0^T ----------------
__global__ __launch_bounds__(256) void k_gemm0(const float* __restrict__ nf,
                                               const float* __restrict__ e2n,
                                               const float* __restrict__ W0,
                                               float* __restrict__ p)
{
    __shared__ float Ws[32 * 160];
    for (int t = threadIdx.x; t < 32 * 160; t += 256) Ws[t] = W0[t];
    __syncthreads();
    int i = blockIdx.x * 256 + threadIdx.x;
    float acc[32];
#pragma unroll
    for (int o = 0; o < 32; o++) acc[o] = 0.f;
    const float4* row  = reinterpret_cast<const float4*>(nf  + (long)i * NF_);
    const float4* row2 = reinterpret_cast<const float4*>(e2n + (long)i * EF_);
    const float4* Ws4  = reinterpret_cast<const float4*>(Ws);
    for (int d4 = 0; d4 < NF_ / 4; ++d4) {
        float4 v = row[d4];
#pragma unroll
        for (int o = 0; o < 32; o++) {
            float4 w = Ws4[o * 40 + d4];
            acc[o] += v.x * w.x + v.y * w.y + v.z * w.z + v.w * w.w;
        }
    }
#pragma unroll
    for (int d4 = 0; d4 < EF_ / 4; ++d4) {
        float4 v = row2[d4];
#pragma unroll
        for (int o = 0; o < 32; o++) {
            float4 w = Ws4[o * 40 + 32 + d4];
            acc[o] += v.x * w.x + v.y * w.y + v.z * w.z + v.w * w.w;
        }
    }
    float4* p4 = reinterpret_cast<float4*>(p + (long)i * 32);
#pragma unroll
    for (int o4 = 0; o4 < 8; o4++)
        p4[o4] = make_float4(acc[o4*4], acc[o4*4+1], acc[o4*4+2], acc[o4*4+3]);
}

// ---------------- fused: pair-gather + tanh + NEXT-layer projection ----------------
__global__ __launch_bounds__(256) void k_gather_proj(const int* __restrict__ row_start,
                                                     const unsigned int* __restrict__ adjp,
                                                     const float* __restrict__ deg,
                                                     const float* __restrict__ p_in,
                                                     const float* __restrict__ b,
                                                     float* __restrict__ cat, int out_off,
                                                     const float* __restrict__ Wn,
                                                     float* __restrict__ p_out)
{
    __shared__ float WT[32 * 32];
    for (int idx = threadIdx.x; idx < 1024; idx += 256) {
        int k = idx >> 5, o = idx & 31;
        WT[idx] = Wn[o * 32 + k];
    }
    __syncthreads();
    int gid = xcd_swz(blockIdx.x, gridDim.x) * 256 + threadIdx.x;   // (N/2)*32 threads
    int pr = gid >> 5, o = gid & 31;
    int i0 = pr * 2, i1 = i0 + 1;
    int s0 = row_start[i0], s1 = row_start[i1];
    float dg0 = deg[i0], dg1 = deg[i1];
    int n0 = cnt_of(dg0), n1 = cnt_of(dg1);
    int bng = i0 & ~2047;
    float r0, r1;
    row_gather_pair(adjp, s0, n0, s1, n1, bng,
                    reinterpret_cast<const f4v*>(p_in), o, r0, r1);
    float bo = b[o];
    float a0 = p_in[(long)i0 * 32 + o] + r0;
    float a1 = p_in[(long)i1 * 32 + o] + r1;
    float t0 = tanhf((a0 + bo) / dg0);
    float t1 = tanhf((a1 + bo) / dg1);
    __builtin_nontemporal_store(t0, &cat[(long)i0 * CATLD + out_off + o]);
    __builtin_nontemporal_store(t1, &cat[(long)i1 * CATLD + out_off + o]);
    float acc0 = 0.f, acc1 = 0.f;
#pragma unroll
    for (int k = 0; k < 32; k++) {
        float w = WT[k * 32 + o];
        acc0 += __shfl(t0, k, 32) * w;
        acc1 += __shfl(t1, k, 32) * w;
    }
    p_out[(long)i0 * 32 + o] = acc0;
    p_out[(long)i1 * 32 + o] = acc1;
}

// ---------------- pair-gather + tanh + 1-wide W3 projection (layer 2) ----------------
__global__ __launch_bounds__(256) void k_gather_act32(const int* __restrict__ row_start,
                                                      const unsigned int* __restrict__ adjp,
                                                      const float* __restrict__ deg,
                                                      const float* __restrict__ p,
                                                      const float* __restrict__ b,
                                                      float* __restrict__ cat, int out_off,
                                                      const float* __restrict__ W3,
                                                      float* __restrict__ p1)
{
    int gid = xcd_swz(blockIdx.x, gridDim.x) * 256 + threadIdx.x;   // (N/2)*32 threads
    int pr = gid >> 5, o = gid & 31;
    int i0 = pr * 2, i1 = i0 + 1;
    int s0 = row_start[i0], s1 = row_start[i1];
    float dg0 = deg[i0], dg1 = deg[i1];
    int n0 = cnt_of(dg0), n1 = cnt_of(dg1);
    int bng = i0 & ~2047;
    float r0, r1;
    row_gather_pair(adjp, s0, n0, s1, n1, bng,
                    reinterpret_cast<const f4v*>(p), o, r0, r1);
    float bo = b[o];
    float a0 = p[(long)i0 * 32 + o] + r0;
    float a1 = p[(long)i1 * 32 + o] + r1;
    float t0 = tanhf((a0 + bo) / dg0);
    float t1 = tanhf((a1 + bo) / dg1);
    __builtin_nontemporal_store(t0, &cat[(long)i0 * CATLD + out_off + o]);
    __builtin_nontemporal_store(t1, &cat[(long)i1 * CATLD + out_off + o]);
    float w3 = W3[o];
    float q0 = t0 * w3, q1 = t1 * w3;
#pragma unroll
    for (int sft = 16; sft > 0; sft >>= 1) {
        q0 += __shfl_xor(q0, sft, 32);
        q1 += __shfl_xor(q1, sft, 32);
    }
    if (o == 0) { p1[i0] = q0; p1[i1] = q1; }
}

// ---------------- layer 3 gather + act (1-wide, chunk-8) -> DENSE t3 ----------------
__global__ __launch_bounds__(256) void k_gather_act1(const int* __restrict__ row_start,
                                                     const unsigned int* __restrict__ adjp,
                                                     const float* __restrict__ deg,
                                                     const float* __restrict__ p1,
                                                     const float* __restrict__ b,
                                                     float* __restrict__ t3)
{
    int i = blockIdx.x * 256 + threadIdx.x;     // N threads
    int s = row_start[i];
    float dg = deg[i];
    int n = cnt_of(dg);
    int bn = i & ~2047;
    float a = p1[i];
    int k = 0;
    for (; k + 8 <= n; k += 8) {
        unsigned int v0 = adjp[s + k + 0], v1 = adjp[s + k + 1], v2 = adjp[s + k + 2], v3 = adjp[s + k + 3];
        unsigned int v4 = adjp[s + k + 4], v5 = adjp[s + k + 5], v6 = adjp[s + k + 6], v7 = adjp[s + k + 7];
        float f0 = p1[bn + (v0 & 2047u)], f1 = p1[bn + (v1 & 2047u)];
        float f2 = p1[bn + (v2 & 2047u)], f3 = p1[bn + (v3 & 2047u)];
        float f4 = p1[bn + (v4 & 2047u)], f5 = p1[bn + (v5 & 2047u)];
        float f6 = p1[bn + (v6 & 2047u)], f7 = p1[bn + (v7 & 2047u)];
        a += ((f0 + f1) + (f2 + f3)) + ((f4 + f5) + (f6 + f7));
    }
    for (; k < n; k++) a += p1[bn + (adjp[s + k] & 2047u)];
    t3[i] = tanhf((a + b[0]) / dg);
}

// ---------------- sortpooling top-K + conv/MLP head (one block per graph) ----------------
__global__ __launch_bounds__(256) void k_topk_head(
    const float* __restrict__ t3,
    const float* __restrict__ cat,
    const float* __restrict__ Wc1, const float* __restrict__ bc1,
    const float* __restrict__ Wc2, const float* __restrict__ bc2,
    const float* __restrict__ Wh,  const float* __restrict__ bh,
    const float* __restrict__ Wo,  const float* __restrict__ bo,
    float* __restrict__ out)
{
    const int g = blockIdx.x, tid = threadIdx.x;
    __shared__ float vals[NPG_];
    __shared__ int   sel[K_];
    __shared__ float selv[K_];
    __shared__ float Pm[K_][TLD_];
    __shared__ float y1[C1_][K_];
    __shared__ float y2[C1_][P2_];
    __shared__ float dd[DENSE_];
    __shared__ float h1s[HID_];
    __shared__ float zz[NCLS_];
    const long gbase = (long)g * NPG_;

    for (int j = tid; j < NPG_; j += 256) vals[j] = t3[gbase + j];
    __syncthreads();

    // top-K, ties -> lower index (jax.lax.top_k semantics); wave 0 only, no barriers
    if (tid < 64) {
        for (int k = 0; k < K_; k++) {
            float bv = -INFINITY; int bj = NPG_;
#pragma unroll
            for (int m = 0; m < 32; m++) {
                int j = m * 64 + tid;               // ascending j per lane -> strict > keeps lowest
                float v = vals[j];
                if (v > bv) { bv = v; bj = j; }
            }
#pragma unroll
            for (int s = 32; s > 0; s >>= 1) {
                float ov = __shfl_xor(bv, s);
                int   oj = __shfl_xor(bj, s);
                if (ov > bv || (ov == bv && oj < bj)) { bv = ov; bj = oj; }
            }
            if (tid == 0) { sel[k] = bj; selv[k] = bv; vals[bj] = -INFINITY; }
        }
    }
    __syncthreads();

    for (int t = tid; t < K_ * TLD_; t += 256) {
        int k = t / TLD_, d = t % TLD_;
        Pm[k][d] = (d < 96) ? cat[(gbase + sel[k]) * CATLD + d] : selv[k];
    }
    __syncthreads();

    for (int t = tid; t < C1_ * K_; t += 256) {
        int c = t / K_, k = t % K_;
        float a = bc1[c];
        for (int d = 0; d < TLD_; d++) a += Pm[k][d] * Wc1[c * TLD_ + d];
        y1[c][k] = fmaxf(a, 0.f);
    }
    __syncthreads();

    for (int t = tid; t < C1_ * P2_; t += 256) {
        int c = t / P2_, u = t % P2_;
        y2[c][u] = fmaxf(y1[c][2 * u], y1[c][2 * u + 1]);
    }
    __syncthreads();

    for (int t = tid; t < C2_ * U_; t += 256) {
        int c2 = t / U_, u = t % U_;
        float a = bc2[c2];
        for (int c = 0; c < C1_; c++)
#pragma unroll
            for (int w = 0; w < KW2_; w++)
                a += y2[c][u + w] * Wc2[(c2 * C1_ + c) * KW2_ + w];
        dd[t] = fmaxf(a, 0.f);
    }
    __syncthreads();

    if (tid < HID_) {
        float a = bh[tid];
        for (int i = 0; i < DENSE_; i++) a += dd[i] * Wh[tid * DENSE_ + i];
        h1s[tid] = fmaxf(a, 0.f);
    }
    __syncthreads();

    if (tid < NCLS_) {
        float a = bo[tid];
        for (int j = 0; j < HID_; j++) a += h1s[j] * Wo[tid * HID_ + j];
        zz[tid] = a;
    }
    __syncthreads();

    if (tid == 0) {
        float m = zz[0];
        for (int c = 1; c < NCLS_; c++) m = fmaxf(m, zz[c]);
        float s = 0.f;
        for (int c = 0; c < NCLS_; c++) s += expf(zz[c] - m);
        float lse = m + logf(s);
        for (int c = 0; c < NCLS_; c++) out[g * NCLS_ + c] = zz[c] - lse;
    }
}

// ---------------- host launch ----------------
extern "C" void kernel_launch(void* const* d_in, const int* in_sizes, int n_in,
                              void* d_out, int out_size, void* d_ws, size_t ws_size,
                              hipStream_t stream)
{
    const float* nf  = (const float*)d_in[0];
    const float* ef  = (const float*)d_in[1];
    const float* deg = (const float*)d_in[2];
    const float* W0  = (const float*)d_in[3];  const float* b0  = (const float*)d_in[4];
    const float* W1  = (const float*)d_in[5];  const float* b1  = (const float*)d_in[6];
    const float* W2  = (const float*)d_in[7];  const float* b2  = (const float*)d_in[8];
    const float* W3  = (const float*)d_in[9];  const float* b3  = (const float*)d_in[10];
    const float* Wc1 = (const float*)d_in[11]; const float* bc1 = (const float*)d_in[12];
    const float* Wc2 = (const float*)d_in[13]; const float* bc2 = (const float*)d_in[14];
    const float* Wh  = (const float*)d_in[15]; const float* bh  = (const float*)d_in[16];
    const float* Wo  = (const float*)d_in[17]; const float* bo  = (const float*)d_in[18];
    const int* erow  = (const int*)d_in[19];
    const int* ecol  = (const int*)d_in[20];
    float* out = (float*)d_out;

    // ---- workspace layout ----
    char* wsb = (char*)d_ws;
    float* e2n       = (float*)wsb;                       wsb += (size_t)N_ * 32 * 4;   // 16 MB
    float* pA        = (float*)wsb;                       wsb += (size_t)N_ * 32 * 4;   // 16 MB
    float* pB        = (float*)wsb;                       wsb += (size_t)N_ * 32 * 4;   // 16 MB
    float* cat       = (float*)wsb;                       wsb += (size_t)N_ * CATLD * 4;// 64 MB
    float* p1        = (float*)wsb;                       wsb += (size_t)N_ * 4;        // 0.5 MB
    float* t3        = (float*)wsb;                       wsb += (size_t)N_ * 4;        // 0.5 MB
    int*   row_start = (int*)wsb;                         wsb += (size_t)N_ * 4;
    unsigned int* adjp = (unsigned int*)wsb;              /* 8 MB */

    // hist / cursor_blk (4 MB each) overlay pA / pB — both dead until k_gemm0 / k_gather_proj
    int* hist       = (int*)pA;
    int* cursor_blk = (int*)pB;

    // ---- CSR build, atomic-free, XCD-co-located, packed ----
    k_hist<<<NCSRB, 256, 0, stream>>>(erow, hist);
    k_scanall<<<B_, 256, 0, stream>>>(deg, hist, row_start, cursor_blk);
    k_fillc<<<NCSRB, 256, 0, stream>>>(erow, ecol, cursor_blk, adjp);

    // ---- e2n via gather ----
    k_e2n_gather<<<N_ * 32 / 256, 256, 0, stream>>>(ef, row_start, deg, adjp, e2n);

    // ---- layer 0 projection ----
    k_gemm0<<<N_ / 256, 256, 0, stream>>>(nf, e2n, W0, pA);
    // ---- layer 0 pool/act + W1 projection (2 rows per lane-group) ----
    k_gather_proj<<<N_ * 16 / 256, 256, 0, stream>>>(row_start, adjp, deg, pA, b0, cat, 0, W1, pB);
    // ---- layer 1 pool/act + W2 projection ----
    k_gather_proj<<<N_ * 16 / 256, 256, 0, stream>>>(row_start, adjp, deg, pB, b1, cat, 32, W2, pA);
    // ---- layer 2 pool/act + W3 projection (1-wide) ----
    k_gather_act32<<<N_ * 16 / 256, 256, 0, stream>>>(row_start, adjp, deg, pA, b2, cat, 64, W3, p1);
    // ---- layer 3 pool/act -> dense t3 ----
    k_gather_act1<<<N_ / 256, 256, 0, stream>>>(row_start, adjp, deg, p1, b3, t3);

    // ---- sortpooling + head ----
    k_topk_head<<<B_, 256, 0, stream>>>(t3, cat, Wc1, bc1, Wc2, bc2, Wh, bh, Wo, bo, out);
}